// Round 5
// baseline (147.151 us; speedup 1.0000x reference)
//
#include <hip/hip_runtime.h>
#include <hip/hip_bf16.h>

typedef __attribute__((ext_vector_type(8))) short bf16x8;
typedef __attribute__((ext_vector_type(4))) float f32x4;

#define BAND 24576   // one X band buffer: [slot4][row6][col64][16B]

// ---------------- weight synthesis: softmax(alphas) + circulant averages ----
__global__ void wsynth_kernel(const float* __restrict__ W,
                              const float* __restrict__ alphas,
                              const float* __restrict__ gumbels,
                              __hip_bfloat16* __restrict__ Wr) {
    int tid = blockIdx.x * 256 + threadIdx.x;   // 65536 threads: one per (o,i)
    int o = tid >> 8, i = tid & 255;

    float a[7]; float mx = -1e30f;
    for (int j = 0; j < 7; ++j) { a[j] = alphas[j] + 1.0e-4f * gumbels[j]; mx = fmaxf(mx, a[j]); }
    float s = 0.f;
    for (int j = 0; j < 7; ++j) { a[j] = __expf(a[j] - mx); s += a[j]; }
    float invs = 1.0f / s;
    for (int j = 0; j < 7; ++j) a[j] *= invs;

    float acc[9];
    const float* w0 = W + ((size_t)(o * 256 + i)) * 9;
    for (int t = 0; t < 9; ++t) acc[t] = a[0] * w0[t];

    for (int idx = 1; idx < 7; ++idx) {
        int b = 1 << idx;
        int r = o & (b - 1), sc = i & (b - 1);
        int d = (sc - r) & (b - 1);
        int qb = o - r, pb = i - sc;
        float sum[9];
        for (int t = 0; t < 9; ++t) sum[t] = 0.f;
        for (int t = 0; t < b; ++t) {
            const float* wp = W + ((size_t)((qb + t) * 256 + pb + ((t + d) & (b - 1)))) * 9;
            #pragma unroll
            for (int tp = 0; tp < 9; ++tp) sum[tp] += wp[tp];
        }
        float sc2 = a[idx] / (float)b;
        for (int tp = 0; tp < 9; ++tp) acc[tp] += sc2 * sum[tp];
    }
    // layout [tap][o][c] so conv A-operand k (=c) is contiguous
    for (int tp = 0; tp < 9; ++tp)
        Wr[((size_t)(tp * 256 + o)) * 256 + i] = __float2bfloat16(acc[tp]);
}

// ---------------- conv helpers ----------------------------------------------
union BFPack { short s[8]; bf16x8 v; };

__device__ __forceinline__ bf16x8 pack8(const float* f) {
    BFPack p;
    #pragma unroll
    for (int j = 0; j < 8; ++j) {
        __hip_bfloat16 h = __float2bfloat16(f[j]);
        p.s[j] = *reinterpret_cast<short*>(&h);
    }
    return p.v;
}

// load one band (6 rows x 64 cols x 32 ch) worth of this thread's share from
// fp32 NCHW, border-zeroed, converted to bf16 in-register.
__device__ __forceinline__ void stage_load(const float* __restrict__ xb, int ch0, int y0,
                                           int g, int px, bf16x8 (&sv)[3]) {
    #pragma unroll
    for (int rr = 0; rr < 3; ++rr) {
        int pxt = px + rr * 128;
        int row = y0 - 1 + (pxt >> 6);
        int col = (pxt & 63) - 1;
        bool ok = ((unsigned)row < 56u) && ((unsigned)col < 56u);
        int rowc = row < 0 ? 0 : (row > 55 ? 55 : row);
        int colc = col < 0 ? 0 : (col > 55 ? 55 : col);
        const float* p = xb + (size_t)(ch0 + g * 8) * 3136 + rowc * 56 + colc;
        float tmp[8];
        #pragma unroll
        for (int j = 0; j < 8; ++j) {
            float v = p[(size_t)j * 3136];
            tmp[j] = ok ? v : 0.f;
        }
        sv[rr] = pack8(tmp);
    }
}

__device__ __forceinline__ void stage_write(char* dst, int g, int px, const bf16x8 (&sv)[3]) {
    #pragma unroll
    for (int rr = 0; rr < 3; ++rr)
        *reinterpret_cast<bf16x8*>(dst + g * 6144 + (px + rr * 128) * 16) = sv[rr];
}

// ---------------- chunk pair: 18 tap-steps, 2 barriers, reg read-ahead ------
template<bool LAST>
__device__ __forceinline__ void chunk_pair(
    int cp, char* smem, const float* __restrict__ xb,
    const __hip_bfloat16* const (&aPtr)[4],
    const int (&bOff)[7], int y0, int g, int px,
    bf16x8 (&afr)[2][4], bf16x8 (&bfA)[2][4],
    f32x4 (&acc)[4][7])
{
    const int cp64 = cp * 64;          // element offset of chunk 2cp in a W row
    #pragma unroll
    for (int u = 0; u < 2; ++u) {
        bf16x8 sv[3];
        #pragma unroll
        for (int r = 0; r < 9; ++r) {
            const int cur = (u + r) & 1, nxt = cur ^ 1;
            const int dy = r / 3 - 1, dx = r % 3 - 1;
            const int timm = (dy * 64 + dx) * 16;
            const char* bandCur = smem + u * BAND;

            // prefetch frags for step kk+1 (af: global L2; bfA: LDS)
            if (!(LAST && u == 1 && r == 8)) {
                const int tapn = (r == 8) ? 0 : r + 1;
                const int eoff = tapn * 65536 + (u + (r == 8 ? 1 : 0)) * 32;
                #pragma unroll
                for (int nf = 0; nf < 4; ++nf)
                    afr[nxt][nf] = *(const bf16x8*)(aPtr[nf] + cp64 + eoff);
                const int dyn = tapn / 3 - 1, dxn = tapn % 3 - 1;
                const int timn = (dyn * 64 + dxn) * 16;
                const char* bandN = smem + ((r == 8) ? (u ^ 1) : u) * BAND;
                #pragma unroll
                for (int mf = 0; mf < 4; ++mf)
                    bfA[nxt][mf] = *(const bf16x8*)(bandN + bOff[mf] + timn);
            }
            // JIT read of this step's remaining 3 pixel frags (covered by 16 MFMAs)
            bf16x8 bfB[3];
            #pragma unroll
            for (int mf = 0; mf < 3; ++mf)
                bfB[mf] = *(const bf16x8*)(bandCur + bOff[4 + mf] + timm);

            // issue next band's global loads early (chunk c+1)
            if (r == 0 && !(LAST && u == 1))
                stage_load(xb, (2 * cp + u + 1) * 32, y0, g, px, sv);

            __builtin_amdgcn_s_setprio(1);
            #pragma unroll
            for (int nf = 0; nf < 4; ++nf)
                #pragma unroll
                for (int mf = 0; mf < 4; ++mf)
                    acc[nf][mf] = __builtin_amdgcn_mfma_f32_16x16x32_bf16(
                        afr[cur][nf], bfA[cur][mf], acc[nf][mf], 0, 0, 0);
            #pragma unroll
            for (int nf = 0; nf < 4; ++nf)
                #pragma unroll
                for (int mf = 0; mf < 3; ++mf)
                    acc[nf][4 + mf] = __builtin_amdgcn_mfma_f32_16x16x32_bf16(
                        afr[cur][nf], bfB[mf], acc[nf][4 + mf], 0, 0, 0);
            __builtin_amdgcn_s_setprio(0);

            // write next band into the other buffer (overwritten one is 2 chunks old)
            if (r == 6 && !(LAST && u == 1))
                stage_write(smem + (u ^ 1) * BAND, g, px, sv);
            // single barrier per chunk: band(c+1) complete & all waves past band(c-1)
            if (r == 7 && !(LAST && u == 1))
                __syncthreads();
        }
    }
}

__global__ __launch_bounds__(512, 2) void conv_kernel(
        const float* __restrict__ x,
        const __hip_bfloat16* __restrict__ Wr,
        float* __restrict__ out) {
    __shared__ char smem[2 * BAND];

    const int tid = threadIdx.x;
    const int w = tid >> 6, lane = tid & 63, l15 = lane & 15, q = lane >> 4;
    const int bid = blockIdx.x;            // 224 blocks: 14 per image, 4 rows each
    const int bimg = bid / 14;
    const int y0 = (bid - bimg * 14) * 4;

    const int wn = (w & 3) << 6;           // wave och base (4 waves x 64)
    const int wm = (w >> 2) * 112;         // wave pixel base (2 waves x 112)
    const int g = tid >> 7, px = tid & 127;

    const float* xb = x + (size_t)bimg * 256 * 3136;

    const __hip_bfloat16* aPtr[4];
    #pragma unroll
    for (int nf = 0; nf < 4; ++nf)
        aPtr[nf] = Wr + (wn + nf * 16 + l15) * 256 + q * 8;

    int bOff[7];
    #pragma unroll
    for (int mf = 0; mf < 7; ++mf) {
        int p = wm + mf * 16 + l15;            // local pixel 0..223
        int y = p / 56, xx = p - y * 56;
        bOff[mf] = q * 6144 + ((y + 1) * 64 + (xx + 1)) * 16;
    }

    f32x4 acc[4][7];
    #pragma unroll
    for (int a1 = 0; a1 < 4; ++a1)
        #pragma unroll
        for (int a2 = 0; a2 < 7; ++a2)
            acc[a1][a2] = (f32x4){0.f, 0.f, 0.f, 0.f};

    bf16x8 afr[2][4], bfA[2][4];

    // prologue: stage band 0, then read frags(0) into set 0
    {
        bf16x8 sv[3];
        stage_load(xb, 0, y0, g, px, sv);
        stage_write(smem, g, px, sv);
    }
    __syncthreads();
    {
        const int timm = (-64 - 1) * 16;       // tap 0: dy=-1, dx=-1
        #pragma unroll
        for (int nf = 0; nf < 4; ++nf) afr[0][nf] = *(const bf16x8*)(aPtr[nf]);
        #pragma unroll
        for (int mf = 0; mf < 4; ++mf) bfA[0][mf] = *(const bf16x8*)(smem + bOff[mf] + timm);
    }

    for (int cp = 0; cp < 3; ++cp)
        chunk_pair<false>(cp, smem, xb, aPtr, bOff, y0, g, px, afr, bfA, acc);
    chunk_pair<true>(3, smem, xb, aPtr, bOff, y0, g, px, afr, bfA, acc);

    // epilogue: och from (q,nf,rr), pixel from (wm,mf,l15)
    const int nb = wn + q * 4;
    const size_t obB = (size_t)bimg * 256 * 3136;
    #pragma unroll
    for (int mf = 0; mf < 7; ++mf) {
        int pm = y0 * 56 + wm + mf * 16 + l15;
        #pragma unroll
        for (int nf = 0; nf < 4; ++nf) {
            #pragma unroll
            for (int rr = 0; rr < 4; ++rr)
                out[obB + (size_t)(nb + nf * 16 + rr) * 3136 + pm] = acc[nf][mf][rr];
        }
    }
}

extern "C" void kernel_launch(void* const* d_in, const int* in_sizes, int n_in,
                              void* d_out, int out_size, void* d_ws, size_t ws_size,
                              hipStream_t stream) {
    const float* x       = (const float*)d_in[0];
    const float* weight  = (const float*)d_in[1];
    const float* alphas  = (const float*)d_in[2];
    const float* gumbels = (const float*)d_in[3];
    float* out = (float*)d_out;

    __hip_bfloat16* Wr = (__hip_bfloat16*)d_ws;   // 9*256*256 bf16 = 1.125 MB

    hipLaunchKernelGGL(wsynth_kernel, dim3(256), dim3(256), 0, stream,
                       weight, alphas, gumbels, Wr);
    hipLaunchKernelGGL(conv_kernel,   dim3(224), dim3(512), 0, stream,
                       x, Wr, out);
}

// Round 6
// 111.020 us; speedup vs baseline: 1.3255x; 1.3255x over previous
//
#include <hip/hip_runtime.h>
#include <hip/hip_bf16.h>

typedef __attribute__((ext_vector_type(8))) short bf16x8;
typedef __attribute__((ext_vector_type(4))) float f32x4;

#define WR_OFF   27557888   // Wr right after Xp (16*58*58*256*2B) in d_ws
// S (diag sums, 580608 floats = 2.32MB) overlays Xp start: consumed by wsynth
// BEFORE zero_border/pad write Xp (stream-ordered).

// conv LDS map (dynamic, 114688 B): 2 X bands @ 24576, then 4 W bufs @ 16384
#define BAND     24576
#define WBUF_OFF 49152
#define WBUF_SZ  16384

// ---------------- per-level circulant diagonal sums -------------------------
// S[level][q][p][d][tap] = sum_{t<b} W[q*b+t][p*b + ((t+d)&(b-1))][tap]
__global__ void diagsum_kernel(const float* __restrict__ W, float* __restrict__ S) {
    int t = blockIdx.x * 256 + threadIdx.x;   // 64512 threads exactly
    int idx, n, lvlOff;
    if (t < 32768)      { idx = 1; n = t;          lvlOff = 0; }
    else if (t < 49152) { idx = 2; n = t - 32768;  lvlOff = 294912; }
    else if (t < 57344) { idx = 3; n = t - 49152;  lvlOff = 442368; }
    else if (t < 61440) { idx = 4; n = t - 57344;  lvlOff = 516096; }
    else if (t < 63488) { idx = 5; n = t - 61440;  lvlOff = 552960; }
    else                { idx = 6; n = t - 63488;  lvlOff = 571392; }
    int b = 1 << idx;
    int d = n & (b - 1);
    int qp = n >> idx;
    int p = qp & ((256 >> idx) - 1);
    int q = qp >> (8 - idx);
    float s[9];
    #pragma unroll
    for (int tp = 0; tp < 9; ++tp) s[tp] = 0.f;
    for (int tt = 0; tt < b; ++tt) {
        const float* wp = W + ((size_t)((q * b + tt) * 256 + p * b + ((tt + d) & (b - 1)))) * 9;
        #pragma unroll
        for (int tp = 0; tp < 9; ++tp) s[tp] += wp[tp];
    }
    float* o = S + (size_t)lvlOff + (size_t)n * 9;
    #pragma unroll
    for (int tp = 0; tp < 9; ++tp) o[tp] = s[tp];
}

// ---------------- weight synthesis: softmax + gather of diag sums -----------
__global__ void wsynth_kernel(const float* __restrict__ W,
                              const float* __restrict__ alphas,
                              const float* __restrict__ gumbels,
                              const float* __restrict__ S,
                              __hip_bfloat16* __restrict__ Wr) {
    int tid = blockIdx.x * 256 + threadIdx.x;   // 65536 threads: one per (o,i)
    int o = tid >> 8, i = tid & 255;

    float a[7]; float mx = -1e30f;
    for (int j = 0; j < 7; ++j) { a[j] = alphas[j] + 1.0e-4f * gumbels[j]; mx = fmaxf(mx, a[j]); }
    float s = 0.f;
    for (int j = 0; j < 7; ++j) { a[j] = __expf(a[j] - mx); s += a[j]; }
    float invs = 1.0f / s;
    for (int j = 0; j < 7; ++j) a[j] *= invs;

    float acc[9];
    const float* w0 = W + ((size_t)(o * 256 + i)) * 9;
    #pragma unroll
    for (int t = 0; t < 9; ++t) acc[t] = a[0] * w0[t];

    const int lvlOff[7] = {0, 0, 294912, 442368, 516096, 552960, 571392};
    int dif = i - o;
    #pragma unroll
    for (int idx = 1; idx < 7; ++idx) {
        int b = 1 << idx;
        int q = o >> idx, p = i >> idx, d = dif & (b - 1);
        int n = ((q * (256 >> idx) + p) << idx) + d;
        const float* sp = S + lvlOff[idx] + (size_t)n * 9;
        float sc = a[idx] / (float)b;
        #pragma unroll
        for (int tp = 0; tp < 9; ++tp) acc[tp] += sc * sp[tp];
    }
    // layout [tap][o][c] so conv A-operand k (=c) is contiguous
    #pragma unroll
    for (int tp = 0; tp < 9; ++tp)
        Wr[((size_t)(tp * 256 + o)) * 256 + i] = __float2bfloat16(acc[tp]);
}

// ---------------- zero only the pad frame of Xp [16][58][58][256] -----------
__global__ void zero_border_kernel(__hip_bfloat16* __restrict__ Xp) {
    int t = blockIdx.x * 256 + threadIdx.x;   // 16*228*256 = 933888 exactly
    int c = t & 255;
    int pp = t >> 8;
    int b = pp / 228;
    int p = pp - b * 228;
    int y, x;
    if (p < 58)       { y = 0;            x = p; }
    else if (p < 116) { y = 57;           x = p - 58; }
    else if (p < 172) { y = 1 + (p - 116); x = 0; }
    else              { y = 1 + (p - 172); x = 57; }
    Xp[((size_t)(b * 58 + y) * 58 + x) * 256 + c] = __float2bfloat16(0.f);
}

// ---------------- NCHW fp32 -> zero-padded NHWC bf16 [16][58][58][256] ------
__global__ void pad_nhwc_kernel(const float* __restrict__ x,
                                __hip_bfloat16* __restrict__ Xp) {
    __shared__ float t[64][65];
    int p0 = blockIdx.x * 64;       // pixel chunk within image (3136/64 = 49)
    int c0 = blockIdx.y * 64;       // channel chunk
    int b  = blockIdx.z;            // image
    int lane = threadIdx.x & 63;
    int grp  = threadIdx.x >> 6;    // 0..3

    const float* src = x + ((size_t)(b * 256 + c0)) * 3136 + p0;
    #pragma unroll
    for (int it = 0; it < 16; ++it) {
        int c = it * 4 + grp;
        t[c][lane] = src[(size_t)c * 3136 + lane];   // coalesced reads
    }
    __syncthreads();
    #pragma unroll
    for (int it = 0; it < 16; ++it) {
        int pl = it * 4 + grp;
        int P = p0 + pl;
        int y = P / 56, xx = P - y * 56;
        Xp[(((size_t)(b * 58 + y + 1)) * 58 + (xx + 1)) * 256 + c0 + lane] =
            __float2bfloat16(t[lane][pl]);           // coalesced 128B writes
    }
}

// ---------------- conv: 224x256 tile, 1 barrier/step, counted vmcnt ---------
__device__ __forceinline__ void gload16(const __hip_bfloat16* g, char* l) {
    __builtin_amdgcn_global_load_lds(
        (const __attribute__((address_space(1))) void*)g,
        (__attribute__((address_space(3))) void*)l, 16, 0, 0);
}

template<int N> __device__ __forceinline__ void gate() {
    if constexpr (N == 0)      asm volatile("s_waitcnt vmcnt(0)" ::: "memory");
    else if constexpr (N == 2) asm volatile("s_waitcnt vmcnt(2)" ::: "memory");
    else if constexpr (N == 4) asm volatile("s_waitcnt vmcnt(4)" ::: "memory");
    else if constexpr (N == 7) asm volatile("s_waitcnt vmcnt(7)" ::: "memory");
}

// One c-chunk (32 ch): 9 tap-steps. Per step: stage-issue, ds_read frags,
// 28 MFMA (compiler-scheduled lgkm waits), counted vmcnt gate, ONE barrier.
template<bool LAST>
__device__ __forceinline__ void chunk_body(
    int cc, char* smem,
    const int (&aOff)[4], const int (&bOff)[7],
    const __hip_bfloat16* wSrc0, const __hip_bfloat16* const (&xSrc)[3],
    int tid, f32x4 (&acc)[4][7])
{
    const char* xb = smem + (cc & 1) * BAND;
    #pragma unroll
    for (int r = 0; r < 9; ++r) {
        // 1. stage W pair for step kk+3 into buf (cc+r+3)&3
        if (!LAST || r <= 5) {
            const int tap2 = (r < 6) ? r + 3 : r - 6;
            const int cc2  = (r < 6) ? cc : cc + 1;
            const __hip_bfloat16* s = wSrc0 + tap2 * 65536 + cc2 * 32;
            char* d = smem + WBUF_OFF + ((cc + r + 3) & 3) * WBUF_SZ + tid * 16;
            gload16(s, d);
            gload16(s + 16, d + 8192);
        }
        // 2. stage next X band (3 gloads; drained 3 steps later)
        if (!LAST && r == 3) {
            char* d = smem + ((cc + 1) & 1) * BAND + tid * 16;
            #pragma unroll
            for (int it = 0; it < 3; ++it)
                gload16(xSrc[it] + (cc + 1) * 32, d + it * 8192);
        }
        // 3. this step's frags (LDS; compiler inserts precise lgkm waits)
        const char* wb = smem + WBUF_OFF + ((cc + r) & 3) * WBUF_SZ;
        const int dy = r / 3 - 1, dx = r % 3 - 1;
        const int timm = (dy * 64 + dx) * 16;
        bf16x8 af[4], bfv[7];
        #pragma unroll
        for (int nf = 0; nf < 4; ++nf) af[nf] = *(const bf16x8*)(wb + aOff[nf]);
        #pragma unroll
        for (int mf = 0; mf < 7; ++mf) bfv[mf] = *(const bf16x8*)(xb + bOff[mf] + timm);
        // 4. MFMA cluster
        __builtin_amdgcn_s_setprio(1);
        #pragma unroll
        for (int nf = 0; nf < 4; ++nf)
            #pragma unroll
            for (int mf = 0; mf < 7; ++mf)
                acc[nf][mf] = __builtin_amdgcn_mfma_f32_16x16x32_bf16(
                    af[nf], bfv[mf], acc[nf][mf], 0, 0, 0);
        __builtin_amdgcn_s_setprio(0);
        // 5. counted gate: next step's buffer landed; never vmcnt(0) mid-loop
        if constexpr (LAST) {
            if (r <= 5)      gate<4>();
            else if (r == 6) gate<2>();
            else if (r == 7) gate<0>();
        } else {
            if (r == 3 || r == 4 || r == 5) gate<7>();
            else                            gate<4>();
        }
        // 6. one barrier per step
        if (!(LAST && r == 8)) __builtin_amdgcn_s_barrier();
    }
}

__global__ __launch_bounds__(512, 2) void conv_kernel(
        const __hip_bfloat16* __restrict__ Xp,
        const __hip_bfloat16* __restrict__ Wr,
        float* __restrict__ out) {
    extern __shared__ char smem[];

    const int tid = threadIdx.x;
    const int w = tid >> 6, lane = tid & 63, l15 = lane & 15, q = lane >> 4;
    const int bid = blockIdx.x;            // 224 blocks: 14 per image, 4 rows
    const int bimg = bid / 14;
    const int y0 = (bid - bimg * 14) * 4;

    const int wn = (w & 3) << 6;           // wave och base (4 waves x 64)
    const int wm = (w >> 2) * 112;         // wave pixel base (2 waves x 112)

    // W staging: thread -> (och = tid&255, slots tid>>8 and +2); dest = tid*16
    const __hip_bfloat16* wSrc0 = Wr + (tid & 255) * 256 + (tid >> 8) * 8;

    // X band staging: 3 chunks/thread; chunk = tid + it*512 -> (slot, row, xcol)
    const __hip_bfloat16* xSrc[3];
    #pragma unroll
    for (int it = 0; it < 3; ++it) {
        int chunk = tid + it * 512;
        int slot = chunk / 384;
        int rem  = chunk - slot * 384;
        int row = rem >> 6, xcol = rem & 63;   // xcol>=58 reads in-bounds garbage (unused)
        xSrc[it] = Xp + (((size_t)(bimg * 58 + y0 + row)) * 58 + xcol) * 256 + slot * 8;
    }

    // frag read offsets (bytes); conflict-free [slot][row][16B] layouts
    int aOff[4];
    #pragma unroll
    for (int nf = 0; nf < 4; ++nf) aOff[nf] = q * 4096 + (wn + nf * 16 + l15) * 16;
    int bOff[7];
    #pragma unroll
    for (int mf = 0; mf < 7; ++mf) {
        int p = wm + mf * 16 + l15;            // local pixel 0..223
        int y = p / 56, xx = p - y * 56;
        bOff[mf] = q * 6144 + ((y + 1) * 64 + (xx + 1)) * 16;
    }

    f32x4 acc[4][7];
    #pragma unroll
    for (int a1 = 0; a1 < 4; ++a1)
        #pragma unroll
        for (int a2 = 0; a2 < 7; ++a2)
            acc[a1][a2] = (f32x4){0.f, 0.f, 0.f, 0.f};

    // prologue: band 0 (oldest), then W bufs for steps 0,1,2
    {
        char* d = smem + tid * 16;
        #pragma unroll
        for (int it = 0; it < 3; ++it) gload16(xSrc[it], d + it * 8192);
        #pragma unroll
        for (int t = 0; t < 3; ++t) {
            const __hip_bfloat16* s = wSrc0 + t * 65536;
            char* dw = smem + WBUF_OFF + t * WBUF_SZ + tid * 16;
            gload16(s, dw);
            gload16(s + 16, dw + 8192);
        }
    }
    gate<4>();   // band0 + W0 landed; W1,W2 stay in flight
    __builtin_amdgcn_s_barrier();

    for (int cc = 0; cc < 7; ++cc)
        chunk_body<false>(cc, smem, aOff, bOff, wSrc0, xSrc, tid, acc);
    chunk_body<true>(7, smem, aOff, bOff, wSrc0, xSrc, tid, acc);

    // epilogue: och from (q,nf,rr), pixel from (wm,mf,l15); 64B runs
    const int nb = wn + q * 4;
    const size_t obB = (size_t)bimg * 256 * 3136;
    #pragma unroll
    for (int mf = 0; mf < 7; ++mf) {
        int pm = y0 * 56 + wm + mf * 16 + l15;
        #pragma unroll
        for (int nf = 0; nf < 4; ++nf) {
            #pragma unroll
            for (int rr = 0; rr < 4; ++rr)
                out[obB + (size_t)(nb + nf * 16 + rr) * 3136 + pm] = acc[nf][mf][rr];
        }
    }
}

extern "C" void kernel_launch(void* const* d_in, const int* in_sizes, int n_in,
                              void* d_out, int out_size, void* d_ws, size_t ws_size,
                              hipStream_t stream) {
    const float* x       = (const float*)d_in[0];
    const float* weight  = (const float*)d_in[1];
    const float* alphas  = (const float*)d_in[2];
    const float* gumbels = (const float*)d_in[3];
    float* out = (float*)d_out;

    __hip_bfloat16* Xp = (__hip_bfloat16*)d_ws;
    float*          S  = (float*)d_ws;            // overlays Xp; used pre-pad
    __hip_bfloat16* Wr = (__hip_bfloat16*)((char*)d_ws + WR_OFF);

    hipFuncSetAttribute(reinterpret_cast<const void*>(conv_kernel),
                        hipFuncAttributeMaxDynamicSharedMemorySize, 114688);

    hipLaunchKernelGGL(diagsum_kernel,     dim3(252),       dim3(256), 0, stream,
                       weight, S);
    hipLaunchKernelGGL(wsynth_kernel,      dim3(256),       dim3(256), 0, stream,
                       weight, alphas, gumbels, S, Wr);
    hipLaunchKernelGGL(zero_border_kernel, dim3(3648),      dim3(256), 0, stream, Xp);
    hipLaunchKernelGGL(pad_nhwc_kernel,    dim3(49, 4, 16), dim3(256), 0, stream, x, Xp);
    hipLaunchKernelGGL(conv_kernel,        dim3(224),       dim3(512), 114688, stream,
                       Xp, Wr, out);
}

// Round 7
// 96.740 us; speedup vs baseline: 1.5211x; 1.1476x over previous
//
#include <hip/hip_runtime.h>
#include <hip/hip_bf16.h>

typedef __attribute__((ext_vector_type(8))) short bf16x8;
typedef __attribute__((ext_vector_type(4))) float f32x4;

#define WR_OFF   27557888   // Wr right after Xp (16*58*58*256*2B) in d_ws
// S (diag sums, 580608 floats = 2.32MB) overlays Xp start: consumed by wsynth
// BEFORE pad (which writes Xp). Stream-ordered.

#define BAND 24576          // one X band buffer: [slot4][row6][col64][16B]

// ---------------- per-level circulant diagonal sums -------------------------
// S[level][q][p][d][tap] = sum_{t<b} W[q*b+t][p*b + ((t+d)&(b-1))][tap]
__global__ void diagsum_kernel(const float* __restrict__ W, float* __restrict__ S) {
    int t = blockIdx.x * 256 + threadIdx.x;   // 64512 threads exactly
    int idx, n, lvlOff;
    if (t < 32768)      { idx = 1; n = t;          lvlOff = 0; }
    else if (t < 49152) { idx = 2; n = t - 32768;  lvlOff = 294912; }
    else if (t < 57344) { idx = 3; n = t - 49152;  lvlOff = 442368; }
    else if (t < 61440) { idx = 4; n = t - 57344;  lvlOff = 516096; }
    else if (t < 63488) { idx = 5; n = t - 61440;  lvlOff = 552960; }
    else                { idx = 6; n = t - 63488;  lvlOff = 571392; }
    int b = 1 << idx;
    int d = n & (b - 1);
    int qp = n >> idx;
    int p = qp & ((256 >> idx) - 1);
    int q = qp >> (8 - idx);
    float s[9];
    #pragma unroll
    for (int tp = 0; tp < 9; ++tp) s[tp] = 0.f;
    for (int tt = 0; tt < b; ++tt) {
        const float* wp = W + ((size_t)((q * b + tt) * 256 + p * b + ((tt + d) & (b - 1)))) * 9;
        #pragma unroll
        for (int tp = 0; tp < 9; ++tp) s[tp] += wp[tp];
    }
    float* o = S + (size_t)lvlOff + (size_t)n * 9;
    #pragma unroll
    for (int tp = 0; tp < 9; ++tp) o[tp] = s[tp];
}

// ---------------- weight synthesis: softmax + gather of diag sums -----------
// Output layout = conv fragment layout: elem(tap,o,c) =
//   tap*65536 + (c>>5)*8192 + ((c>>3)&3)*2048 + o*8 + (c&7)
__global__ void wsynth_kernel(const float* __restrict__ W,
                              const float* __restrict__ alphas,
                              const float* __restrict__ gumbels,
                              const float* __restrict__ S,
                              __hip_bfloat16* __restrict__ Wr) {
    int tid = blockIdx.x * 256 + threadIdx.x;   // 65536 threads: one per (o,i)
    int o = tid >> 8, i = tid & 255;

    float a[7]; float mx = -1e30f;
    for (int j = 0; j < 7; ++j) { a[j] = alphas[j] + 1.0e-4f * gumbels[j]; mx = fmaxf(mx, a[j]); }
    float s = 0.f;
    for (int j = 0; j < 7; ++j) { a[j] = __expf(a[j] - mx); s += a[j]; }
    float invs = 1.0f / s;
    for (int j = 0; j < 7; ++j) a[j] *= invs;

    float acc[9];
    const float* w0 = W + ((size_t)(o * 256 + i)) * 9;
    #pragma unroll
    for (int t = 0; t < 9; ++t) acc[t] = a[0] * w0[t];

    const int lvlOff[7] = {0, 0, 294912, 442368, 516096, 552960, 571392};
    int dif = i - o;
    #pragma unroll
    for (int idx = 1; idx < 7; ++idx) {
        int b = 1 << idx;
        int q = o >> idx, p = i >> idx, d = dif & (b - 1);
        int n = ((q * (256 >> idx) + p) << idx) + d;
        const float* sp = S + lvlOff[idx] + (size_t)n * 9;
        float sc = a[idx] / (float)b;
        #pragma unroll
        for (int tp = 0; tp < 9; ++tp) acc[tp] += sc * sp[tp];
    }
    const size_t eb = (size_t)(i >> 5) * 8192 + ((i >> 3) & 3) * 2048 + o * 8 + (i & 7);
    #pragma unroll
    for (int tp = 0; tp < 9; ++tp)
        Wr[(size_t)tp * 65536 + eb] = __float2bfloat16(acc[tp]);
}

// ------- NCHW fp32 -> zero-padded NHWC bf16 [16][58][58][256] + border ------
__global__ void pad_nhwc_kernel(const float* __restrict__ x,
                                __hip_bfloat16* __restrict__ Xp) {
    // fused border zeroing: 933888 border elems over 802816 threads (1-2 each)
    {
        int bl = (blockIdx.z * 4 + blockIdx.y) * 49 + blockIdx.x;  // 0..3135
        int L = bl * 256 + threadIdx.x;
        for (int e = L; e < 933888; e += 802816) {
            int c = e & 255;
            int pp = e >> 8;
            int b = pp / 228;
            int p = pp - b * 228;
            int y, xx;
            if (p < 58)       { y = 0;             xx = p; }
            else if (p < 116) { y = 57;            xx = p - 58; }
            else if (p < 172) { y = 1 + (p - 116); xx = 0; }
            else              { y = 1 + (p - 172); xx = 57; }
            Xp[((size_t)(b * 58 + y) * 58 + xx) * 256 + c] = __float2bfloat16(0.f);
        }
    }
    __shared__ float t[64][65];
    int p0 = blockIdx.x * 64;       // pixel chunk within image (3136/64 = 49)
    int c0 = blockIdx.y * 64;       // channel chunk
    int b  = blockIdx.z;            // image
    int lane = threadIdx.x & 63;
    int grp  = threadIdx.x >> 6;    // 0..3

    const float* src = x + ((size_t)(b * 256 + c0)) * 3136 + p0;
    #pragma unroll
    for (int it = 0; it < 16; ++it) {
        int c = it * 4 + grp;
        t[c][lane] = src[(size_t)c * 3136 + lane];   // coalesced reads
    }
    __syncthreads();
    #pragma unroll
    for (int it = 0; it < 16; ++it) {
        int pl = it * 4 + grp;
        int P = p0 + pl;
        int y = P / 56, xx = P - y * 56;
        Xp[(((size_t)(b * 58 + y + 1)) * 58 + (xx + 1)) * 256 + c0 + lane] =
            __float2bfloat16(t[lane][pl]);           // coalesced 128B writes
    }
}

// ---------------- conv: 224x256 tile; W global->reg; X-only LDS -------------
__device__ __forceinline__ void gload16(const __hip_bfloat16* g, char* l) {
    __builtin_amdgcn_global_load_lds(
        (const __attribute__((address_space(1))) void*)g,
        (__attribute__((address_space(3))) void*)l, 16, 0, 0);
}

template<int N> __device__ __forceinline__ void gate() {
    if constexpr (N == 0)      asm volatile("s_waitcnt vmcnt(0)" ::: "memory");
    else if constexpr (N == 4) asm volatile("s_waitcnt vmcnt(4)" ::: "memory");
}

// Two c-chunks (cc = 2cp+u, u unrolled so afr parity is compile-time).
// Per step: prefetch next A-frags (global->reg), ds_read 7 B-frags, 28 MFMA.
// One counted gate + barrier per chunk (band double-buffer hand-off).
template<bool LAST>
__device__ __forceinline__ void chunk_pair(
    int cp, char* smem, const char* aBase,
    const int (&bOff)[7], const __hip_bfloat16* const (&xSrc)[3],
    int tid, bf16x8 (&afr)[2][4], f32x4 (&acc)[4][7])
{
    #pragma unroll
    for (int u = 0; u < 2; ++u) {
        const int cc = 2 * cp + u;
        const char* xb = smem + u * BAND;          // cc&1 == u (2cp even)
        #pragma unroll
        for (int r = 0; r < 9; ++r) {
            const int cur = (u + r) & 1, nxt = cur ^ 1;
            // 1. prefetch A-frags for next step (L2/L1-resident Wr)
            if (!(LAST && u == 1 && r == 8)) {
                const int tapn = (r == 8) ? 0 : r + 1;
                const int aoff = tapn * 131072 + (cc + (r == 8 ? 1 : 0)) * 16384;
                #pragma unroll
                for (int nf = 0; nf < 4; ++nf)
                    afr[nxt][nf] = *(const bf16x8*)(aBase + aoff + nf * 256);
            }
            // 2. stage next X band (3 gloads; consumed next chunk)
            if (!(LAST && u == 1) && r == 3) {
                char* d = smem + (u ^ 1) * BAND + tid * 16;
                #pragma unroll
                for (int it = 0; it < 3; ++it)
                    gload16(xSrc[it] + (cc + 1) * 32, d + it * 8192);
            }
            // 3. this step's B-frags from LDS (compiler-precise lgkm waits)
            const int dy = r / 3 - 1, dx = r % 3 - 1;
            const int timm = (dy * 64 + dx) * 16;
            bf16x8 bfv[7];
            #pragma unroll
            for (int mf = 0; mf < 7; ++mf)
                bfv[mf] = *(const bf16x8*)(xb + bOff[mf] + timm);
            // 4. MFMA cluster
            __builtin_amdgcn_s_setprio(1);
            #pragma unroll
            for (int nf = 0; nf < 4; ++nf)
                #pragma unroll
                for (int mf = 0; mf < 7; ++mf)
                    acc[nf][mf] = __builtin_amdgcn_mfma_f32_16x16x32_bf16(
                        afr[cur][nf], bfv[mf], acc[nf][mf], 0, 0, 0);
            __builtin_amdgcn_s_setprio(0);
            // 5. chunk boundary: band landed (vmcnt counted) + barrier
            if (r == 8 && !(LAST && u == 1)) {
                gate<4>();   // drains band gloads (oldest); newest afr stay in flight
                __builtin_amdgcn_s_barrier();
            }
        }
    }
}

__global__ __launch_bounds__(512, 2) void conv_kernel(
        const __hip_bfloat16* __restrict__ Xp,
        const __hip_bfloat16* __restrict__ Wr,
        float* __restrict__ out) {
    __shared__ char smem[2 * BAND];

    const int tid = threadIdx.x;
    const int w = tid >> 6, lane = tid & 63, l15 = lane & 15, q = lane >> 4;
    const int bid = blockIdx.x;            // 224 blocks: 14 per image, 4 rows
    const int bimg = bid / 14;
    const int y0 = (bid - bimg * 14) * 4;

    const int wn = (w & 3) << 6;           // wave och base (4 waves x 64)
    const int wm = (w >> 2) * 112;         // wave pixel base (2 waves x 112)

    // A-frag per-lane base (bytes into Wr): [tap][cc][q][och][8]
    const char* aBase = (const char*)Wr + q * 4096 + (wn + l15) * 16;

    // X band staging: 3 chunks/thread; chunk = tid + it*512 -> (slot, row, xcol)
    const __hip_bfloat16* xSrc[3];
    #pragma unroll
    for (int it = 0; it < 3; ++it) {
        int chunk = tid + it * 512;
        int slot = chunk / 384;
        int rem  = chunk - slot * 384;
        int row = rem >> 6, xcol = rem & 63;   // xcol>=58 reads in-bounds garbage (unused)
        xSrc[it] = Xp + (((size_t)(bimg * 58 + y0 + row)) * 58 + xcol) * 256 + slot * 8;
    }

    // B-frag read offsets (bytes); conflict-free [slot][row][16B] layout
    int bOff[7];
    #pragma unroll
    for (int mf = 0; mf < 7; ++mf) {
        int p = wm + mf * 16 + l15;            // local pixel 0..223
        int y = p / 56, xx = p - y * 56;
        bOff[mf] = q * 6144 + ((y + 1) * 64 + (xx + 1)) * 16;
    }

    f32x4 acc[4][7];
    #pragma unroll
    for (int a1 = 0; a1 < 4; ++a1)
        #pragma unroll
        for (int a2 = 0; a2 < 7; ++a2)
            acc[a1][a2] = (f32x4){0.f, 0.f, 0.f, 0.f};

    bf16x8 afr[2][4];

    // prologue: band 0 into buffer 0; A-frags for step (tap0, cc0)
    {
        char* d = smem + tid * 16;
        #pragma unroll
        for (int it = 0; it < 3; ++it) gload16(xSrc[it], d + it * 8192);
    }
    #pragma unroll
    for (int nf = 0; nf < 4; ++nf)
        afr[0][nf] = *(const bf16x8*)(aBase + nf * 256);
    gate<0>();
    __builtin_amdgcn_s_barrier();

    for (int cp = 0; cp < 3; ++cp)
        chunk_pair<false>(cp, smem, aBase, bOff, xSrc, tid, afr, acc);
    chunk_pair<true>(3, smem, aBase, bOff, xSrc, tid, afr, acc);

    // epilogue: och from (q,nf,rr), pixel from (wm,mf,l15); 64B runs
    const int nb = wn + q * 4;
    const size_t obB = (size_t)bimg * 256 * 3136;
    #pragma unroll
    for (int mf = 0; mf < 7; ++mf) {
        int pm = y0 * 56 + wm + mf * 16 + l15;
        #pragma unroll
        for (int nf = 0; nf < 4; ++nf) {
            #pragma unroll
            for (int rr = 0; rr < 4; ++rr)
                out[obB + (size_t)(nb + nf * 16 + rr) * 3136 + pm] = acc[nf][mf][rr];
        }
    }
}

extern "C" void kernel_launch(void* const* d_in, const int* in_sizes, int n_in,
                              void* d_out, int out_size, void* d_ws, size_t ws_size,
                              hipStream_t stream) {
    const float* x       = (const float*)d_in[0];
    const float* weight  = (const float*)d_in[1];
    const float* alphas  = (const float*)d_in[2];
    const float* gumbels = (const float*)d_in[3];
    float* out = (float*)d_out;

    __hip_bfloat16* Xp = (__hip_bfloat16*)d_ws;
    float*          S  = (float*)d_ws;            // overlays Xp; used pre-pad
    __hip_bfloat16* Wr = (__hip_bfloat16*)((char*)d_ws + WR_OFF);

    hipLaunchKernelGGL(diagsum_kernel,  dim3(252),       dim3(256), 0, stream,
                       weight, S);
    hipLaunchKernelGGL(wsynth_kernel,   dim3(256),       dim3(256), 0, stream,
                       weight, alphas, gumbels, S, Wr);
    hipLaunchKernelGGL(pad_nhwc_kernel, dim3(49, 4, 16), dim3(256), 0, stream,
                       x, Xp);
    hipLaunchKernelGGL(conv_kernel,     dim3(224),       dim3(512), 0, stream,
                       Xp, Wr, out);
}

// Round 8
// 96.569 us; speedup vs baseline: 1.5238x; 1.0018x over previous
//
#include <hip/hip_runtime.h>
#include <hip/hip_bf16.h>

typedef __attribute__((ext_vector_type(8))) short bf16x8;
typedef __attribute__((ext_vector_type(4))) float f32x4;

#define WR_OFF   27557888   // Wr right after Xp (16*58*58*256*2B) in d_ws
// S (diag sums, 580608 floats = 2.32MB) overlays Xp start: consumed by wsynth
// BEFORE pad (which writes Xp). Stream-ordered.

#define BAND 24576          // one X band buffer: [slot4][row6][col64][16B]

// ---------------- per-level circulant diagonal sums -------------------------
// S[level][q][p][d][tap] = sum_{t<b} W[q*b+t][p*b + ((t+d)&(b-1))][tap]
__global__ void diagsum_kernel(const float* __restrict__ W, float* __restrict__ S) {
    int t = blockIdx.x * 256 + threadIdx.x;   // 64512 threads exactly
    int idx, n, lvlOff;
    if (t < 32768)      { idx = 1; n = t;          lvlOff = 0; }
    else if (t < 49152) { idx = 2; n = t - 32768;  lvlOff = 294912; }
    else if (t < 57344) { idx = 3; n = t - 49152;  lvlOff = 442368; }
    else if (t < 61440) { idx = 4; n = t - 57344;  lvlOff = 516096; }
    else if (t < 63488) { idx = 5; n = t - 61440;  lvlOff = 552960; }
    else                { idx = 6; n = t - 63488;  lvlOff = 571392; }
    int b = 1 << idx;
    int d = n & (b - 1);
    int qp = n >> idx;
    int p = qp & ((256 >> idx) - 1);
    int q = qp >> (8 - idx);
    float s[9];
    #pragma unroll
    for (int tp = 0; tp < 9; ++tp) s[tp] = 0.f;
    for (int tt = 0; tt < b; ++tt) {
        const float* wp = W + ((size_t)((q * b + tt) * 256 + p * b + ((tt + d) & (b - 1)))) * 9;
        #pragma unroll
        for (int tp = 0; tp < 9; ++tp) s[tp] += wp[tp];
    }
    float* o = S + (size_t)lvlOff + (size_t)n * 9;
    #pragma unroll
    for (int tp = 0; tp < 9; ++tp) o[tp] = s[tp];
}

// ---------------- weight synthesis: softmax + gather of diag sums -----------
// Output layout = conv fragment layout: elem(tap,o,c) =
//   tap*65536 + (c>>5)*8192 + ((c>>3)&3)*2048 + o*8 + (c&7)
__global__ void wsynth_kernel(const float* __restrict__ W,
                              const float* __restrict__ alphas,
                              const float* __restrict__ gumbels,
                              const float* __restrict__ S,
                              __hip_bfloat16* __restrict__ Wr) {
    int tid = blockIdx.x * 256 + threadIdx.x;   // 65536 threads: one per (o,i)
    int o = tid >> 8, i = tid & 255;

    float a[7]; float mx = -1e30f;
    for (int j = 0; j < 7; ++j) { a[j] = alphas[j] + 1.0e-4f * gumbels[j]; mx = fmaxf(mx, a[j]); }
    float s = 0.f;
    for (int j = 0; j < 7; ++j) { a[j] = __expf(a[j] - mx); s += a[j]; }
    float invs = 1.0f / s;
    for (int j = 0; j < 7; ++j) a[j] *= invs;

    float acc[9];
    const float* w0 = W + ((size_t)(o * 256 + i)) * 9;
    #pragma unroll
    for (int t = 0; t < 9; ++t) acc[t] = a[0] * w0[t];

    const int lvlOff[7] = {0, 0, 294912, 442368, 516096, 552960, 571392};
    int dif = i - o;
    #pragma unroll
    for (int idx = 1; idx < 7; ++idx) {
        int b = 1 << idx;
        int q = o >> idx, p = i >> idx, d = dif & (b - 1);
        int n = ((q * (256 >> idx) + p) << idx) + d;
        const float* sp = S + lvlOff[idx] + (size_t)n * 9;
        float sc = a[idx] / (float)b;
        #pragma unroll
        for (int tp = 0; tp < 9; ++tp) acc[tp] += sc * sp[tp];
    }
    const size_t eb = (size_t)(i >> 5) * 8192 + ((i >> 3) & 3) * 2048 + o * 8 + (i & 7);
    #pragma unroll
    for (int tp = 0; tp < 9; ++tp)
        Wr[(size_t)tp * 65536 + eb] = __float2bfloat16(acc[tp]);
}

// ------- NCHW fp32 -> zero-padded NHWC bf16 [16][58][58][256] + border ------
__global__ void pad_nhwc_kernel(const float* __restrict__ x,
                                __hip_bfloat16* __restrict__ Xp) {
    // fused border zeroing: 933888 border elems over 802816 threads (1-2 each)
    {
        int bl = (blockIdx.z * 4 + blockIdx.y) * 49 + blockIdx.x;  // 0..3135
        int L = bl * 256 + threadIdx.x;
        for (int e = L; e < 933888; e += 802816) {
            int c = e & 255;
            int pp = e >> 8;
            int b = pp / 228;
            int p = pp - b * 228;
            int y, xx;
            if (p < 58)       { y = 0;             xx = p; }
            else if (p < 116) { y = 57;            xx = p - 58; }
            else if (p < 172) { y = 1 + (p - 116); xx = 0; }
            else              { y = 1 + (p - 172); xx = 57; }
            Xp[((size_t)(b * 58 + y) * 58 + xx) * 256 + c] = __float2bfloat16(0.f);
        }
    }
    __shared__ float t[64][65];
    int p0 = blockIdx.x * 64;       // pixel chunk within image (3136/64 = 49)
    int c0 = blockIdx.y * 64;       // channel chunk
    int b  = blockIdx.z;            // image
    int lane = threadIdx.x & 63;
    int grp  = threadIdx.x >> 6;    // 0..3

    const float* src = x + ((size_t)(b * 256 + c0)) * 3136 + p0;
    #pragma unroll
    for (int it = 0; it < 16; ++it) {
        int c = it * 4 + grp;
        t[c][lane] = src[(size_t)c * 3136 + lane];   // coalesced reads
    }
    __syncthreads();
    #pragma unroll
    for (int it = 0; it < 16; ++it) {
        int pl = it * 4 + grp;
        int P = p0 + pl;
        int y = P / 56, xx = P - y * 56;
        Xp[(((size_t)(b * 58 + y + 1)) * 58 + (xx + 1)) * 256 + c0 + lane] =
            __float2bfloat16(t[lane][pl]);           // coalesced 128B writes
    }
}

// ---------------- conv: 224x256 tile; W global->reg; B-frags reg-dbuf -------
__device__ __forceinline__ void gload16(const __hip_bfloat16* g, char* l) {
    __builtin_amdgcn_global_load_lds(
        (const __attribute__((address_space(1))) void*)g,
        (__attribute__((address_space(3))) void*)l, 16, 0, 0);
}

template<int N> __device__ __forceinline__ void gate() {
    if constexpr (N == 0)      asm volatile("s_waitcnt vmcnt(0)" ::: "memory");
    else if constexpr (N == 4) asm volatile("s_waitcnt vmcnt(4)" ::: "memory");
}

// Two c-chunks (cc = 2cp+u, u unrolled so reg-dbuf parity is compile-time).
// Per step r: prefetch A(r+1) global->reg, prefetch B(r+1) LDS->reg,
// sched_barrier pin, 28 MFMA on [cur]. Band staged at r==0; barrier at r==7.
template<bool LAST>
__device__ __forceinline__ void chunk_pair(
    int cp, char* smem, const char* aBase,
    const int (&bOff)[7], const __hip_bfloat16* const (&xSrc)[3],
    int tid, bf16x8 (&afr)[2][4], bf16x8 (&bfv)[2][7], f32x4 (&acc)[4][7])
{
    #pragma unroll
    for (int u = 0; u < 2; ++u) {
        const int cc = 2 * cp + u;
        const char* xb = smem + u * BAND;          // cc&1 == u (2cp even)
        #pragma unroll
        for (int r = 0; r < 9; ++r) {
            const int cur = (u + r) & 1, nxt = cur ^ 1;
            // 0. stage next band right after the chunk barrier (buffer u^1
            //    was fully read by chunk cc-1; vmcnt-FIFO force-drains these
            //    at r==1's A-wait ~1 step later, > HBM latency of cover)
            if (r == 0 && !(LAST && u == 1)) {
                char* d = smem + (u ^ 1) * BAND + tid * 16;
                #pragma unroll
                for (int it = 0; it < 3; ++it)
                    gload16(xSrc[it] + (cc + 1) * 32, d + it * 8192);
            }
            // 1. prefetch A-frags for next step (L2-resident Wr)
            if (!(LAST && u == 1 && r == 8)) {
                const int tapn = (r == 8) ? 0 : r + 1;
                const int aoff = tapn * 131072 + (cc + (r == 8 ? 1 : 0)) * 16384;
                #pragma unroll
                for (int nf = 0; nf < 4; ++nf)
                    afr[nxt][nf] = *(const bf16x8*)(aBase + aoff + nf * 256);
            }
            // 2. prefetch B-frags for next step (reg double-buffer): r<8 from
            //    this band; r==8 from the freshly-landed next band (post-bar)
            if (r < 8) {
                const int tapn = r + 1;
                const int timn = ((tapn / 3 - 1) * 64 + (tapn % 3 - 1)) * 16;
                #pragma unroll
                for (int mf = 0; mf < 7; ++mf)
                    bfv[nxt][mf] = *(const bf16x8*)(xb + bOff[mf] + timn);
            } else if (!(LAST && u == 1)) {
                const int timn = (-64 - 1) * 16;   // tap 0
                const char* xb2 = smem + (u ^ 1) * BAND;
                #pragma unroll
                for (int mf = 0; mf < 7; ++mf)
                    bfv[nxt][mf] = *(const bf16x8*)(xb2 + bOff[mf] + timn);
            }
            // pin: prefetches stay above the MFMA cluster
            __builtin_amdgcn_sched_barrier(0);
            // 3. MFMA cluster on current-step registers
            __builtin_amdgcn_s_setprio(1);
            #pragma unroll
            for (int nf = 0; nf < 4; ++nf)
                #pragma unroll
                for (int mf = 0; mf < 7; ++mf)
                    acc[nf][mf] = __builtin_amdgcn_mfma_f32_16x16x32_bf16(
                        afr[cur][nf], bfv[cur][mf], acc[nf][mf], 0, 0, 0);
            __builtin_amdgcn_s_setprio(0);
            // 4. chunk barrier at r==7: all waves' band gloads are FIFO-drained
            //    (each wave's r==1 A-wait), so after this barrier the next band
            //    is globally visible; r==8 prefetches from it stall-free.
            if (r == 7 && !(LAST && u == 1)) {
                gate<4>();
                __builtin_amdgcn_s_barrier();
            }
        }
    }
}

__global__ __launch_bounds__(512, 2) void conv_kernel(
        const __hip_bfloat16* __restrict__ Xp,
        const __hip_bfloat16* __restrict__ Wr,
        float* __restrict__ out) {
    __shared__ char smem[2 * BAND];

    const int tid = threadIdx.x;
    const int w = tid >> 6, lane = tid & 63, l15 = lane & 15, q = lane >> 4;
    const int bid = blockIdx.x;            // 224 blocks: 14 per image, 4 rows
    const int bimg = bid / 14;
    const int y0 = (bid - bimg * 14) * 4;

    const int wn = (w & 3) << 6;           // wave och base (4 waves x 64)
    const int wm = (w >> 2) * 112;         // wave pixel base (2 waves x 112)

    // A-frag per-lane base (bytes into Wr): [tap][cc][q][och][8]
    const char* aBase = (const char*)Wr + q * 4096 + (wn + l15) * 16;

    // X band staging: 3 chunks/thread; chunk = tid + it*512 -> (slot, row, xcol)
    const __hip_bfloat16* xSrc[3];
    #pragma unroll
    for (int it = 0; it < 3; ++it) {
        int chunk = tid + it * 512;
        int slot = chunk / 384;
        int rem  = chunk - slot * 384;
        int row = rem >> 6, xcol = rem & 63;   // xcol>=58 reads in-bounds garbage (unused)
        xSrc[it] = Xp + (((size_t)(bimg * 58 + y0 + row)) * 58 + xcol) * 256 + slot * 8;
    }

    // B-frag read offsets (bytes); conflict-free [slot][row][16B] layout
    int bOff[7];
    #pragma unroll
    for (int mf = 0; mf < 7; ++mf) {
        int p = wm + mf * 16 + l15;            // local pixel 0..223
        int y = p / 56, xx = p - y * 56;
        bOff[mf] = q * 6144 + ((y + 1) * 64 + (xx + 1)) * 16;
    }

    f32x4 acc[4][7];
    #pragma unroll
    for (int a1 = 0; a1 < 4; ++a1)
        #pragma unroll
        for (int a2 = 0; a2 < 7; ++a2)
            acc[a1][a2] = (f32x4){0.f, 0.f, 0.f, 0.f};

    bf16x8 afr[2][4], bfv[2][7];

    // prologue: band 0 into buffer 0; A+B frags for step (tap0, cc0)
    {
        char* d = smem + tid * 16;
        #pragma unroll
        for (int it = 0; it < 3; ++it) gload16(xSrc[it], d + it * 8192);
    }
    #pragma unroll
    for (int nf = 0; nf < 4; ++nf)
        afr[0][nf] = *(const bf16x8*)(aBase + nf * 256);
    gate<0>();
    __builtin_amdgcn_s_barrier();
    {
        const int timm = (-64 - 1) * 16;       // tap 0: dy=-1, dx=-1
        #pragma unroll
        for (int mf = 0; mf < 7; ++mf)
            bfv[0][mf] = *(const bf16x8*)(smem + bOff[mf] + timm);
    }

    for (int cp = 0; cp < 3; ++cp)
        chunk_pair<false>(cp, smem, aBase, bOff, xSrc, tid, afr, bfv, acc);
    chunk_pair<true>(3, smem, aBase, bOff, xSrc, tid, afr, bfv, acc);

    // epilogue: och from (q,nf,rr), pixel from (wm,mf,l15); 64B runs
    const int nb = wn + q * 4;
    const size_t obB = (size_t)bimg * 256 * 3136;
    #pragma unroll
    for (int mf = 0; mf < 7; ++mf) {
        int pm = y0 * 56 + wm + mf * 16 + l15;
        #pragma unroll
        for (int nf = 0; nf < 4; ++nf) {
            #pragma unroll
            for (int rr = 0; rr < 4; ++rr)
                out[obB + (size_t)(nb + nf * 16 + rr) * 3136 + pm] = acc[nf][mf][rr];
        }
    }
}

extern "C" void kernel_launch(void* const* d_in, const int* in_sizes, int n_in,
                              void* d_out, int out_size, void* d_ws, size_t ws_size,
                              hipStream_t stream) {
    const float* x       = (const float*)d_in[0];
    const float* weight  = (const float*)d_in[1];
    const float* alphas  = (const float*)d_in[2];
    const float* gumbels = (const float*)d_in[3];
    float* out = (float*)d_out;

    __hip_bfloat16* Xp = (__hip_bfloat16*)d_ws;
    float*          S  = (float*)d_ws;            // overlays Xp; used pre-pad
    __hip_bfloat16* Wr = (__hip_bfloat16*)((char*)d_ws + WR_OFF);

    hipLaunchKernelGGL(diagsum_kernel,  dim3(252),       dim3(256), 0, stream,
                       weight, S);
    hipLaunchKernelGGL(wsynth_kernel,   dim3(256),       dim3(256), 0, stream,
                       weight, alphas, gumbels, S, Wr);
    hipLaunchKernelGGL(pad_nhwc_kernel, dim3(49, 4, 16), dim3(256), 0, stream,
                       x, Xp);
    hipLaunchKernelGGL(conv_kernel,     dim3(224),       dim3(512), 0, stream,
                       Xp, Wr, out);
}